// Round 4
// baseline (116.047 us; speedup 1.0000x reference)
//
#include <hip/hip_runtime.h>
#include <hip/hip_bf16.h>

// Chamfer distance, B=4, N=M=8192, D=3, fp32.
// R15: INSTRUMENTATION ROUND. Exact R11 kernel (best: 76.8us), but mega is
// launched 3x back-to-back (idempotent: same inputs -> same part writes,
// serialized on one stream -> absmax 0.0 preserved).
//   Delta vs 76.8 = 2 x (mega_dur + launch_overhead~3us).
//   Delta >= 45us -> mega >= 20us -> attack mega main loop (H1).
//   Delta <= 30us -> mega <= 12us -> fixed overhead dominates; fuse kernels (H2).
// Side benefit: if mega >= 20us it enters rocprof top-5, exposing its
// VGPR/MfmaUtil/VALUBusy/Occupancy counters for the first time.
// Payload (verified absmax 0.0 since R7), k0..15 query x target:
//   -2h.h | -2l.h | -2h.l | qn.1 | 1.tn | 0
//   query vec:  [ax,ay,az, cx,cy,cz, ax,ay,az, qn1,qn2,qn3, 1,1,1, 0]
//   target vec: [hx,hy,hz, hx,hy,hz, lx,ly,lz, 1,1,1, tn1,tn2,tn3, 0]

typedef __attribute__((ext_vector_type(8)))  short short8;
typedef __attribute__((ext_vector_type(16))) float f32x16;

#define BATCH 4
#define NPTS 8192
#define TOTALQ (BATCH * NPTS)   // 32768
#define BLK 256
#define WNT 4                   // 32-col B tiles per wave -> 128 queries/wave
#define BCOLS 512               // query cols per block (4 waves)
#define MSPLIT 8                // target slices per batch
#define MC (NPTS / MSPLIT)      // 1024 targets per block, single LDS stage
#define MT_PER (MC / 32)        // 32 target tiles

__device__ __forceinline__ unsigned short f2bf(float f) {  // RTN-even
    unsigned int u = __float_as_uint(f);
    u += 0x7FFFu + ((u >> 16) & 1u);
    return (unsigned short)(u >> 16);
}
__device__ __forceinline__ float bf2f(unsigned short h) {
    return __uint_as_float(((unsigned int)h) << 16);
}
__device__ __forceinline__ unsigned int pk2(unsigned short a, unsigned short b) {
    return (unsigned int)a | ((unsigned int)b << 16);
}

struct Payload {
    unsigned short hx, hy, hz, lx, ly, lz, n1, n2, n3;
};
__device__ __forceinline__ Payload split_point(float x, float y, float z) {
    Payload P;
    P.hx = f2bf(x);  P.hy = f2bf(y);  P.hz = f2bf(z);
    P.lx = f2bf(x - bf2f(P.hx));
    P.ly = f2bf(y - bf2f(P.hy));
    P.lz = f2bf(z - bf2f(P.hz));
    float nrm = fmaf(z, z, fmaf(y, y, x * x));
    P.n1 = f2bf(nrm);
    float r1 = nrm - bf2f(P.n1);
    P.n2 = f2bf(r1);
    P.n3 = f2bf(r1 - bf2f(P.n2));
    return P;
}

__global__ __launch_bounds__(BLK) void chamfer_mega_kernel(
        const float* __restrict__ pred, const float* __restrict__ target,
        float* __restrict__ part, float* __restrict__ out)
{
    const int dir = blockIdx.z;
    const float* __restrict__ Q  = dir ? target : pred;   // outputs (B cols)
    const float* __restrict__ Tg = dir ? pred : target;   // min-over (A rows, LDS)

    const int nch = blockIdx.x;            // 0..63 (512-query-col chunk)
    const int b   = nch >> 4;              // batch (16 chunks per batch)
    const int ms  = blockIdx.y;            // 0..7 target slice
    const int w    = threadIdx.x >> 6;
    const int lane = threadIdx.x & 63;
    const int c = lane & 31;               // row (A) / col (B) within tile
    const int g = lane >> 5;               // k-half
    const unsigned short ONE = 0x3F80;

    if (blockIdx.x == 0 && blockIdx.y == 0 && blockIdx.z == 0 &&
        threadIdx.x == 0) out[0] = 0.0f;   // consumed after kernel boundary

    __shared__ uint4 ldsb[2][MC];          // 32 KB (two k-halves)

    // ---- stage MC target points: raw read -> payload -> LDS (A operand) ----
    #pragma unroll
    for (int j = 0; j < MC / BLK; ++j) {
        int p = j * BLK + threadIdx.x;
        size_t gp = (size_t)b * NPTS + (size_t)ms * MC + p;
        float x = Tg[3 * gp], y = Tg[3 * gp + 1], z = Tg[3 * gp + 2];
        Payload P = split_point(x, y, z);
        ldsb[0][p] = (uint4){ pk2(P.hx, P.hy), pk2(P.hz, P.hx),
                              pk2(P.hy, P.hz), pk2(P.lx, P.ly) };
        ldsb[1][p] = (uint4){ pk2(P.lz, ONE), pk2(ONE, ONE),
                              pk2(P.n1, P.n2), pk2(P.n3, 0) };
    }

    // ---- B fragments (queries): in-register pack, col = colstart + nt*32 + c ----
    const int colstart = nch * BCOLS + w * (WNT * 32);
    short8 bq[WNT];
    #pragma unroll
    for (int nt = 0; nt < WNT; ++nt) {
        int r = colstart + nt * 32 + c;
        float x = Q[3 * r], y = Q[3 * r + 1], z = Q[3 * r + 2];
        Payload P = split_point(x, y, z);
        unsigned short ax = f2bf(-2.f * bf2f(P.hx)),
                       ay = f2bf(-2.f * bf2f(P.hy)),
                       az = f2bf(-2.f * bf2f(P.hz));
        unsigned short cx = f2bf(-2.f * bf2f(P.lx)),
                       cy = f2bf(-2.f * bf2f(P.ly)),
                       cz = f2bf(-2.f * bf2f(P.lz));
        uint4 h0 = { pk2(ax, ay), pk2(az, cx), pk2(cy, cz), pk2(ax, ay) };
        uint4 h1 = { pk2(az, P.n1), pk2(P.n2, P.n3), pk2(ONE, ONE), pk2(ONE, 0) };
        uint4 sel = g ? h1 : h0;
        bq[nt] = *(short8*)&sel;
    }

    f32x16 acc[WNT];
    #pragma unroll
    for (int nt = 0; nt < WNT; ++nt)
        #pragma unroll
        for (int r = 0; r < 16; ++r) acc[nt][r] = 3.4e38f;

    f32x16 vzero;
    #pragma unroll
    for (int r = 0; r < 16; ++r) vzero[r] = 0.0f;

    __syncthreads();

    const ushort* ldsu = (const ushort*)&ldsb[g][0];   // this lane's k-half

    // ---- main loop: 2 ds_read_b128 (A target tiles) + 8 MFMA + 64 min3 ----
    for (int mt = 0; mt < MT_PER; mt += 2) {
        short8 at0 = *(const short8*)(ldsu + (mt * 32 + c) * 8);
        short8 at1 = *(const short8*)(ldsu + ((mt + 1) * 32 + c) * 8);
        #pragma unroll
        for (int nt = 0; nt < WNT; ++nt) {
            f32x16 d0, d1;
            // A = target tile (LDS), B = query tile (regs); VGPR dst.
            // s_nop pads the MFMA-write -> VALU-read hazard (asm is opaque
            // to the hazard recognizer).
            asm("v_mfma_f32_32x32x16_bf16 %0, %2, %4, %5\n\t"
                "v_mfma_f32_32x32x16_bf16 %1, %3, %4, %5\n\t"
                "s_nop 7\n\t"
                "s_nop 7"
                : "=&v"(d0), "=&v"(d1)
                : "v"(at0), "v"(at1), "v"(bq[nt]), "v"(vzero));
            #pragma unroll
            for (int r = 0; r < 16; ++r)
                acc[nt][r] = fminf(fminf(acc[nt][r], d0[r]), d1[r]); // v_min3
        }
    }

    // ---- epilogue: min over the 16 regs (rows) in-lane + 1 shfl for g ----
    float* rp = part + (size_t)(dir * MSPLIT + ms) * TOTALQ;
    #pragma unroll
    for (int nt = 0; nt < WNT; ++nt) {
        f32x16 v = acc[nt];
        float m0 = fminf(fminf(v[0],  v[1]),  fminf(v[2],  v[3]));
        float m1 = fminf(fminf(v[4],  v[5]),  fminf(v[6],  v[7]));
        float m2 = fminf(fminf(v[8],  v[9]),  fminf(v[10], v[11]));
        float m3 = fminf(fminf(v[12], v[13]), fminf(v[14], v[15]));
        float m  = fminf(fminf(m0, m1), fminf(m2, m3));
        m = fminf(m, __shfl_xor(m, 32, 64));    // fold the two k-half rows
        if (g == 0) rp[colstart + nt * 32 + c] = m;
    }
}

__global__ __launch_bounds__(BLK) void chamfer_reduce_kernel(
        const float* __restrict__ part, float* __restrict__ out)
{
    int gl = blockIdx.x * BLK + threadIdx.x;   // 0..65535
    int dir = gl >> 15, i = gl & (TOTALQ - 1);

    const float* p = part + (size_t)dir * MSPLIT * TOTALQ + i;
    float m = p[0];
    #pragma unroll
    for (int s = 1; s < MSPLIT; ++s)
        m = fminf(m, p[(size_t)s * TOTALQ]);

    float acc = m * (1.0f / (float)TOTALQ);
    #pragma unroll
    for (int off = 32; off > 0; off >>= 1)
        acc += __shfl_down(acc, off, 64);
    __shared__ float wsum[BLK / 64];
    int lane = threadIdx.x & 63, wid = threadIdx.x >> 6;
    if (lane == 0) wsum[wid] = acc;
    __syncthreads();
    if (threadIdx.x == 0) {
        float s = 0.0f;
        #pragma unroll
        for (int wv = 0; wv < BLK / 64; ++wv) s += wsum[wv];
        atomicAdd(out, s);
    }
}

extern "C" void kernel_launch(void* const* d_in, const int* in_sizes, int n_in,
                              void* d_out, int out_size, void* d_ws, size_t ws_size,
                              hipStream_t stream) {
    const float* pred   = (const float*)d_in[0];
    const float* target = (const float*)d_in[1];
    float*       out    = (float*)d_out;
    float*       part   = (float*)d_ws;   // 2 dirs x 8 slices x 32768 = 2 MB

    dim3 grid(TOTALQ / BCOLS, MSPLIT, 2);   // 64 x 8 x 2 = 1024 blocks

    // INSTRUMENTATION: 3 identical (idempotent) mega launches.
    // Delta vs R11's 76.8us = 2 x (mega_dur + launch_overhead).
    hipLaunchKernelGGL(chamfer_mega_kernel, grid, dim3(BLK), 0, stream,
                       pred, target, part, out);
    hipLaunchKernelGGL(chamfer_mega_kernel, grid, dim3(BLK), 0, stream,
                       pred, target, part, out);
    hipLaunchKernelGGL(chamfer_mega_kernel, grid, dim3(BLK), 0, stream,
                       pred, target, part, out);

    hipLaunchKernelGGL(chamfer_reduce_kernel, dim3(2 * TOTALQ / BLK), dim3(BLK),
                       0, stream, (const float*)part, out);
}

// Round 5
// 83.291 us; speedup vs baseline: 1.3933x; 1.3933x over previous
//
#include <hip/hip_runtime.h>
#include <hip/hip_bf16.h>

// Chamfer distance, B=4, N=M=8192, D=3, fp32.
// R16: single-variable change vs R11 (best measured, 76.8us; mega measured
// ~16.5us by R15's 3x-launch probe vs a ~5us issue floor): replace the
// opaque {MFMA,MFMA,s_nop,s_nop} asm block with the
// __builtin_amdgcn_mfma_f32_32x32x16_bf16 intrinsic. The asm block forced a
// serialized issue->16cyc-stall->32cyc-min3 chain per wave (compiler cannot
// interleave across an asm boundary, and "=&v" doubled register demand).
// With the intrinsic the scheduler inserts exactly the needed hazard nops
// and can pipeline next-iteration ds_read/MFMA issue under the current min3
// stream. Operands and math bit-identical (A=target tile, B=query tile,
// C=0) -> absmax 0.0 preserved.
// Payload (verified absmax 0.0 since R7), k0..15 query x target:
//   -2h.h | -2l.h | -2h.l | qn.1 | 1.tn | 0
//   query vec:  [ax,ay,az, cx,cy,cz, ax,ay,az, qn1,qn2,qn3, 1,1,1, 0]
//   target vec: [hx,hy,hz, hx,hy,hz, lx,ly,lz, 1,1,1, tn1,tn2,tn3, 0]

typedef __attribute__((ext_vector_type(8)))  short short8;
typedef __attribute__((ext_vector_type(16))) float f32x16;

#define BATCH 4
#define NPTS 8192
#define TOTALQ (BATCH * NPTS)   // 32768
#define BLK 256
#define WNT 4                   // 32-col B tiles per wave -> 128 queries/wave
#define BCOLS 512               // query cols per block (4 waves)
#define MSPLIT 8                // target slices per batch
#define MC (NPTS / MSPLIT)      // 1024 targets per block, single LDS stage
#define MT_PER (MC / 32)        // 32 target tiles

__device__ __forceinline__ unsigned short f2bf(float f) {  // RTN-even
    unsigned int u = __float_as_uint(f);
    u += 0x7FFFu + ((u >> 16) & 1u);
    return (unsigned short)(u >> 16);
}
__device__ __forceinline__ float bf2f(unsigned short h) {
    return __uint_as_float(((unsigned int)h) << 16);
}
__device__ __forceinline__ unsigned int pk2(unsigned short a, unsigned short b) {
    return (unsigned int)a | ((unsigned int)b << 16);
}

struct Payload {
    unsigned short hx, hy, hz, lx, ly, lz, n1, n2, n3;
};
__device__ __forceinline__ Payload split_point(float x, float y, float z) {
    Payload P;
    P.hx = f2bf(x);  P.hy = f2bf(y);  P.hz = f2bf(z);
    P.lx = f2bf(x - bf2f(P.hx));
    P.ly = f2bf(y - bf2f(P.hy));
    P.lz = f2bf(z - bf2f(P.hz));
    float nrm = fmaf(z, z, fmaf(y, y, x * x));
    P.n1 = f2bf(nrm);
    float r1 = nrm - bf2f(P.n1);
    P.n2 = f2bf(r1);
    P.n3 = f2bf(r1 - bf2f(P.n2));
    return P;
}

__global__ __launch_bounds__(BLK) void chamfer_mega_kernel(
        const float* __restrict__ pred, const float* __restrict__ target,
        float* __restrict__ part, float* __restrict__ out)
{
    const int dir = blockIdx.z;
    const float* __restrict__ Q  = dir ? target : pred;   // outputs (B cols)
    const float* __restrict__ Tg = dir ? pred : target;   // min-over (A rows, LDS)

    const int nch = blockIdx.x;            // 0..63 (512-query-col chunk)
    const int b   = nch >> 4;              // batch (16 chunks per batch)
    const int ms  = blockIdx.y;            // 0..7 target slice
    const int w    = threadIdx.x >> 6;
    const int lane = threadIdx.x & 63;
    const int c = lane & 31;               // row (A) / col (B) within tile
    const int g = lane >> 5;               // k-half
    const unsigned short ONE = 0x3F80;

    if (blockIdx.x == 0 && blockIdx.y == 0 && blockIdx.z == 0 &&
        threadIdx.x == 0) out[0] = 0.0f;   // consumed after kernel boundary

    __shared__ uint4 ldsb[2][MC];          // 32 KB (two k-halves)

    // ---- stage MC target points: raw read -> payload -> LDS (A operand) ----
    #pragma unroll
    for (int j = 0; j < MC / BLK; ++j) {
        int p = j * BLK + threadIdx.x;
        size_t gp = (size_t)b * NPTS + (size_t)ms * MC + p;
        float x = Tg[3 * gp], y = Tg[3 * gp + 1], z = Tg[3 * gp + 2];
        Payload P = split_point(x, y, z);
        ldsb[0][p] = (uint4){ pk2(P.hx, P.hy), pk2(P.hz, P.hx),
                              pk2(P.hy, P.hz), pk2(P.lx, P.ly) };
        ldsb[1][p] = (uint4){ pk2(P.lz, ONE), pk2(ONE, ONE),
                              pk2(P.n1, P.n2), pk2(P.n3, 0) };
    }

    // ---- B fragments (queries): in-register pack, col = colstart + nt*32 + c ----
    const int colstart = nch * BCOLS + w * (WNT * 32);
    short8 bq[WNT];
    #pragma unroll
    for (int nt = 0; nt < WNT; ++nt) {
        int r = colstart + nt * 32 + c;
        float x = Q[3 * r], y = Q[3 * r + 1], z = Q[3 * r + 2];
        Payload P = split_point(x, y, z);
        unsigned short ax = f2bf(-2.f * bf2f(P.hx)),
                       ay = f2bf(-2.f * bf2f(P.hy)),
                       az = f2bf(-2.f * bf2f(P.hz));
        unsigned short cx = f2bf(-2.f * bf2f(P.lx)),
                       cy = f2bf(-2.f * bf2f(P.ly)),
                       cz = f2bf(-2.f * bf2f(P.lz));
        uint4 h0 = { pk2(ax, ay), pk2(az, cx), pk2(cy, cz), pk2(ax, ay) };
        uint4 h1 = { pk2(az, P.n1), pk2(P.n2, P.n3), pk2(ONE, ONE), pk2(ONE, 0) };
        uint4 sel = g ? h1 : h0;
        bq[nt] = *(short8*)&sel;
    }

    f32x16 acc[WNT];
    #pragma unroll
    for (int nt = 0; nt < WNT; ++nt)
        #pragma unroll
        for (int r = 0; r < 16; ++r) acc[nt][r] = 3.4e38f;

    f32x16 vzero;
    #pragma unroll
    for (int r = 0; r < 16; ++r) vzero[r] = 0.0f;

    __syncthreads();

    const ushort* ldsu = (const ushort*)&ldsb[g][0];   // this lane's k-half

    // ---- main loop: 2 ds_read_b128 (A target tiles) + 8 MFMA + 64 min3 ----
    // Intrinsic MFMA: compiler owns hazard padding + cross-iteration
    // scheduling (pipelines next MFMA issue under current min3 stream).
    #pragma unroll 2
    for (int mt = 0; mt < MT_PER; mt += 2) {
        short8 at0 = *(const short8*)(ldsu + (mt * 32 + c) * 8);
        short8 at1 = *(const short8*)(ldsu + ((mt + 1) * 32 + c) * 8);
        #pragma unroll
        for (int nt = 0; nt < WNT; ++nt) {
            f32x16 d0 = __builtin_amdgcn_mfma_f32_32x32x16_bf16(
                            at0, bq[nt], vzero, 0, 0, 0);
            f32x16 d1 = __builtin_amdgcn_mfma_f32_32x32x16_bf16(
                            at1, bq[nt], vzero, 0, 0, 0);
            #pragma unroll
            for (int r = 0; r < 16; ++r)
                acc[nt][r] = fminf(fminf(acc[nt][r], d0[r]), d1[r]); // v_min3
        }
    }

    // ---- epilogue: min over the 16 regs (rows) in-lane + 1 shfl for g ----
    float* rp = part + (size_t)(dir * MSPLIT + ms) * TOTALQ;
    #pragma unroll
    for (int nt = 0; nt < WNT; ++nt) {
        f32x16 v = acc[nt];
        float m0 = fminf(fminf(v[0],  v[1]),  fminf(v[2],  v[3]));
        float m1 = fminf(fminf(v[4],  v[5]),  fminf(v[6],  v[7]));
        float m2 = fminf(fminf(v[8],  v[9]),  fminf(v[10], v[11]));
        float m3 = fminf(fminf(v[12], v[13]), fminf(v[14], v[15]));
        float m  = fminf(fminf(m0, m1), fminf(m2, m3));
        m = fminf(m, __shfl_xor(m, 32, 64));    // fold the two k-half rows
        if (g == 0) rp[colstart + nt * 32 + c] = m;
    }
}

__global__ __launch_bounds__(BLK) void chamfer_reduce_kernel(
        const float* __restrict__ part, float* __restrict__ out)
{
    int gl = blockIdx.x * BLK + threadIdx.x;   // 0..65535
    int dir = gl >> 15, i = gl & (TOTALQ - 1);

    const float* p = part + (size_t)dir * MSPLIT * TOTALQ + i;
    float m = p[0];
    #pragma unroll
    for (int s = 1; s < MSPLIT; ++s)
        m = fminf(m, p[(size_t)s * TOTALQ]);

    float acc = m * (1.0f / (float)TOTALQ);
    #pragma unroll
    for (int off = 32; off > 0; off >>= 1)
        acc += __shfl_down(acc, off, 64);
    __shared__ float wsum[BLK / 64];
    int lane = threadIdx.x & 63, wid = threadIdx.x >> 6;
    if (lane == 0) wsum[wid] = acc;
    __syncthreads();
    if (threadIdx.x == 0) {
        float s = 0.0f;
        #pragma unroll
        for (int wv = 0; wv < BLK / 64; ++wv) s += wsum[wv];
        atomicAdd(out, s);
    }
}

extern "C" void kernel_launch(void* const* d_in, const int* in_sizes, int n_in,
                              void* d_out, int out_size, void* d_ws, size_t ws_size,
                              hipStream_t stream) {
    const float* pred   = (const float*)d_in[0];
    const float* target = (const float*)d_in[1];
    float*       out    = (float*)d_out;
    float*       part   = (float*)d_ws;   // 2 dirs x 8 slices x 32768 = 2 MB

    dim3 grid(TOTALQ / BCOLS, MSPLIT, 2);   // 64 x 8 x 2 = 1024 blocks
    hipLaunchKernelGGL(chamfer_mega_kernel, grid, dim3(BLK), 0, stream,
                       pred, target, part, out);

    hipLaunchKernelGGL(chamfer_reduce_kernel, dim3(2 * TOTALQ / BLK), dim3(BLK),
                       0, stream, (const float*)part, out);
}

// Round 6
// 77.516 us; speedup vs baseline: 1.4971x; 1.0745x over previous
//
#include <hip/hip_runtime.h>
#include <hip/hip_bf16.h>

// Chamfer distance, B=4, N=M=8192, D=3, fp32.
// R17: software-pipelined mega (base = R11 geometry, best measured 76.8us,
// mega ~16.5us via R15's 3x-launch probe vs ~7us dual-pipe floor).
// Mechanism: R11-R16 all consumed each asm block's MFMA results with v_min3
// immediately after the block (16 nop-cyc apart). If VALU reads of a
// VGPR-dst MFMA interlock until the ~32-64cyc matrix op drains, every unit
// serializes issue->stall->min3 and the matrix pipe idles during min3.
// Now: asm block issues unit k's 2 MFMAs; the following C-level min3s
// consume unit k-1's pair (double-buffered p/q, FLT_MAX-seeded so the first
// min3 is a no-op; one drain after the loop). Read distance >= 36 cyc
// (R11 proves 16 suffices -> 2x margin) so the s_nops are deleted.
// sched_barrier(0) after each asm block pins min3s from hoisting above the
// just-issued MFMAs (hipcc hoists reg-only VALU past inline asm).
// Min is associative/commutative -> bit-identical result (absmax 0.0).
// Payload (verified absmax 0.0 since R7), k0..15 query x target:
//   -2h.h | -2l.h | -2h.l | qn.1 | 1.tn | 0
//   query vec:  [ax,ay,az, cx,cy,cz, ax,ay,az, qn1,qn2,qn3, 1,1,1, 0]
//   target vec: [hx,hy,hz, hx,hy,hz, lx,ly,lz, 1,1,1, tn1,tn2,tn3, 0]

typedef __attribute__((ext_vector_type(8)))  short short8;
typedef __attribute__((ext_vector_type(16))) float f32x16;

#define BATCH 4
#define NPTS 8192
#define TOTALQ (BATCH * NPTS)   // 32768
#define BLK 256
#define WNT 4                   // 32-col B tiles per wave -> 128 queries/wave
#define BCOLS 512               // query cols per block (4 waves)
#define MSPLIT 8                // target slices per batch
#define MC (NPTS / MSPLIT)      // 1024 targets per block, single LDS stage
#define MT_PER (MC / 32)        // 32 target tiles

__device__ __forceinline__ unsigned short f2bf(float f) {  // RTN-even
    unsigned int u = __float_as_uint(f);
    u += 0x7FFFu + ((u >> 16) & 1u);
    return (unsigned short)(u >> 16);
}
__device__ __forceinline__ float bf2f(unsigned short h) {
    return __uint_as_float(((unsigned int)h) << 16);
}
__device__ __forceinline__ unsigned int pk2(unsigned short a, unsigned short b) {
    return (unsigned int)a | ((unsigned int)b << 16);
}

struct Payload {
    unsigned short hx, hy, hz, lx, ly, lz, n1, n2, n3;
};
__device__ __forceinline__ Payload split_point(float x, float y, float z) {
    Payload P;
    P.hx = f2bf(x);  P.hy = f2bf(y);  P.hz = f2bf(z);
    P.lx = f2bf(x - bf2f(P.hx));
    P.ly = f2bf(y - bf2f(P.hy));
    P.lz = f2bf(z - bf2f(P.hz));
    float nrm = fmaf(z, z, fmaf(y, y, x * x));
    P.n1 = f2bf(nrm);
    float r1 = nrm - bf2f(P.n1);
    P.n2 = f2bf(r1);
    P.n3 = f2bf(r1 - bf2f(P.n2));
    return P;
}

// Issue 2 MFMAs for the current unit (A-tile pair x one query tile).
#define MFMA2(D0, D1, A0, A1, BQ)                              \
    asm("v_mfma_f32_32x32x16_bf16 %0, %2, %4, %5\n\t"          \
        "v_mfma_f32_32x32x16_bf16 %1, %3, %4, %5"              \
        : "=&v"(D0), "=&v"(D1)                                 \
        : "v"(A0), "v"(A1), "v"(BQ), "v"(vzero))

// Fold the PREVIOUS unit's pair into its accumulator (v_min3).
#define MIN16(NT, D0, D1)                                      \
    _Pragma("unroll")                                          \
    for (int r = 0; r < 16; ++r)                               \
        acc[NT][r] = fminf(fminf(acc[NT][r], (D0)[r]), (D1)[r])

__global__ __launch_bounds__(BLK) void chamfer_mega_kernel(
        const float* __restrict__ pred, const float* __restrict__ target,
        float* __restrict__ part, float* __restrict__ out)
{
    const int dir = blockIdx.z;
    const float* __restrict__ Q  = dir ? target : pred;   // outputs (B cols)
    const float* __restrict__ Tg = dir ? pred : target;   // min-over (A rows, LDS)

    const int nch = blockIdx.x;            // 0..63 (512-query-col chunk)
    const int b   = nch >> 4;              // batch (16 chunks per batch)
    const int ms  = blockIdx.y;            // 0..7 target slice
    const int w    = threadIdx.x >> 6;
    const int lane = threadIdx.x & 63;
    const int c = lane & 31;               // row (A) / col (B) within tile
    const int g = lane >> 5;               // k-half
    const unsigned short ONE = 0x3F80;

    if (blockIdx.x == 0 && blockIdx.y == 0 && blockIdx.z == 0 &&
        threadIdx.x == 0) out[0] = 0.0f;   // consumed after kernel boundary

    __shared__ uint4 ldsb[2][MC];          // 32 KB (two k-halves)

    // ---- stage MC target points: raw read -> payload -> LDS (A operand) ----
    #pragma unroll
    for (int j = 0; j < MC / BLK; ++j) {
        int p = j * BLK + threadIdx.x;
        size_t gp = (size_t)b * NPTS + (size_t)ms * MC + p;
        float x = Tg[3 * gp], y = Tg[3 * gp + 1], z = Tg[3 * gp + 2];
        Payload P = split_point(x, y, z);
        ldsb[0][p] = (uint4){ pk2(P.hx, P.hy), pk2(P.hz, P.hx),
                              pk2(P.hy, P.hz), pk2(P.lx, P.ly) };
        ldsb[1][p] = (uint4){ pk2(P.lz, ONE), pk2(ONE, ONE),
                              pk2(P.n1, P.n2), pk2(P.n3, 0) };
    }

    // ---- B fragments (queries): in-register pack, col = colstart + nt*32 + c ----
    const int colstart = nch * BCOLS + w * (WNT * 32);
    short8 bq[WNT];
    #pragma unroll
    for (int nt = 0; nt < WNT; ++nt) {
        int r = colstart + nt * 32 + c;
        float x = Q[3 * r], y = Q[3 * r + 1], z = Q[3 * r + 2];
        Payload P = split_point(x, y, z);
        unsigned short ax = f2bf(-2.f * bf2f(P.hx)),
                       ay = f2bf(-2.f * bf2f(P.hy)),
                       az = f2bf(-2.f * bf2f(P.hz));
        unsigned short cx = f2bf(-2.f * bf2f(P.lx)),
                       cy = f2bf(-2.f * bf2f(P.ly)),
                       cz = f2bf(-2.f * bf2f(P.lz));
        uint4 h0 = { pk2(ax, ay), pk2(az, cx), pk2(cy, cz), pk2(ax, ay) };
        uint4 h1 = { pk2(az, P.n1), pk2(P.n2, P.n3), pk2(ONE, ONE), pk2(ONE, 0) };
        uint4 sel = g ? h1 : h0;
        bq[nt] = *(short8*)&sel;
    }

    f32x16 acc[WNT];
    #pragma unroll
    for (int nt = 0; nt < WNT; ++nt)
        #pragma unroll
        for (int r = 0; r < 16; ++r) acc[nt][r] = 3.4e38f;

    f32x16 vzero;
    #pragma unroll
    for (int r = 0; r < 16; ++r) vzero[r] = 0.0f;

    // pipeline buffers: p = pending pair from the previous unit.
    // FLT_MAX-seeded so the first MIN16(3, p) is a no-op on acc[3].
    f32x16 p0, p1, q0, q1;
    #pragma unroll
    for (int r = 0; r < 16; ++r) { p0[r] = 3.4e38f; p1[r] = 3.4e38f; }

    __syncthreads();

    const ushort* ldsu = (const ushort*)&ldsb[g][0];   // this lane's k-half

    // ---- main loop, software-pipelined one unit deep ----
    // unit (bq[nt]) issues its 2 MFMAs; the min3s that follow consume the
    // PREVIOUS unit's pair. Unit->acc mapping: bq0->acc0 (folded at unit1),
    // bq1->acc1 (at unit2), bq2->acc2 (at unit3), bq3->acc3 (at next
    // iteration's unit0; final pair drained after the loop).
    #pragma unroll 1
    for (int mt = 0; mt < MT_PER; mt += 2) {
        short8 at0 = *(const short8*)(ldsu + (mt * 32 + c) * 8);
        short8 at1 = *(const short8*)(ldsu + ((mt + 1) * 32 + c) * 8);

        MFMA2(q0, q1, at0, at1, bq[0]);
        __builtin_amdgcn_sched_barrier(0);
        MIN16(3, p0, p1);

        MFMA2(p0, p1, at0, at1, bq[1]);
        __builtin_amdgcn_sched_barrier(0);
        MIN16(0, q0, q1);

        MFMA2(q0, q1, at0, at1, bq[2]);
        __builtin_amdgcn_sched_barrier(0);
        MIN16(1, p0, p1);

        MFMA2(p0, p1, at0, at1, bq[3]);
        __builtin_amdgcn_sched_barrier(0);
        MIN16(2, q0, q1);
    }
    MIN16(3, p0, p1);   // drain the last unit's pair

    // ---- epilogue: min over the 16 regs (rows) in-lane + 1 shfl for g ----
    float* rp = part + (size_t)(dir * MSPLIT + ms) * TOTALQ;
    #pragma unroll
    for (int nt = 0; nt < WNT; ++nt) {
        f32x16 v = acc[nt];
        float m0 = fminf(fminf(v[0],  v[1]),  fminf(v[2],  v[3]));
        float m1 = fminf(fminf(v[4],  v[5]),  fminf(v[6],  v[7]));
        float m2 = fminf(fminf(v[8],  v[9]),  fminf(v[10], v[11]));
        float m3 = fminf(fminf(v[12], v[13]), fminf(v[14], v[15]));
        float m  = fminf(fminf(m0, m1), fminf(m2, m3));
        m = fminf(m, __shfl_xor(m, 32, 64));    // fold the two k-half rows
        if (g == 0) rp[colstart + nt * 32 + c] = m;
    }
}

__global__ __launch_bounds__(BLK) void chamfer_reduce_kernel(
        const float* __restrict__ part, float* __restrict__ out)
{
    int gl = blockIdx.x * BLK + threadIdx.x;   // 0..65535
    int dir = gl >> 15, i = gl & (TOTALQ - 1);

    const float* p = part + (size_t)dir * MSPLIT * TOTALQ + i;
    float m = p[0];
    #pragma unroll
    for (int s = 1; s < MSPLIT; ++s)
        m = fminf(m, p[(size_t)s * TOTALQ]);

    float acc = m * (1.0f / (float)TOTALQ);
    #pragma unroll
    for (int off = 32; off > 0; off >>= 1)
        acc += __shfl_down(acc, off, 64);
    __shared__ float wsum[BLK / 64];
    int lane = threadIdx.x & 63, wid = threadIdx.x >> 6;
    if (lane == 0) wsum[wid] = acc;
    __syncthreads();
    if (threadIdx.x == 0) {
        float s = 0.0f;
        #pragma unroll
        for (int wv = 0; wv < BLK / 64; ++wv) s += wsum[wv];
        atomicAdd(out, s);
    }
}

extern "C" void kernel_launch(void* const* d_in, const int* in_sizes, int n_in,
                              void* d_out, int out_size, void* d_ws, size_t ws_size,
                              hipStream_t stream) {
    const float* pred   = (const float*)d_in[0];
    const float* target = (const float*)d_in[1];
    float*       out    = (float*)d_out;
    float*       part   = (float*)d_ws;   // 2 dirs x 8 slices x 32768 = 2 MB

    dim3 grid(TOTALQ / BCOLS, MSPLIT, 2);   // 64 x 8 x 2 = 1024 blocks
    hipLaunchKernelGGL(chamfer_mega_kernel, grid, dim3(BLK), 0, stream,
                       pred, target, part, out);

    hipLaunchKernelGGL(chamfer_reduce_kernel, dim3(2 * TOTALQ / BLK), dim3(BLK),
                       0, stream, (const float*)part, out);
}